// Round 8
// baseline (161.662 us; speedup 1.0000x reference)
//
#include <hip/hip_runtime.h>
#include <math.h>

// InfoNCE (NT-Xent), N=8192, D=128, fp32 in, scalar fp32 out.
// g = normalize(h)*sqrt(5*log2e) quantized to fp8 e4m3; MFMA fp8 Gram with
// exp2 row/col sums; pos + diag terms exact in fp32 (E5 constant, d12).
// Symmetric passes compute each unordered strip pair once (col sums double
// as transposed row sums). 512-thr blocks, wave tile 64x32 -> 4 waves/SIMD.
// Double-buffered LDS, 1 barrier/tile, prefetch issued after the barrier.

constexpr int D = 128;
constexpr float E5 = 148.4131591025766f;   // e^5 (diag of exp(inter))

typedef __attribute__((ext_vector_type(16))) float f32x16;  // 32x32 MFMA acc

__global__ __launch_bounds__(256) void normalize_kernel(
    const float2* __restrict__ h1, const float2* __restrict__ h2,
    unsigned short* __restrict__ g1b, unsigned short* __restrict__ g2b,
    float* __restrict__ d12, float* __restrict__ acc, float* __restrict__ out,
    int N)
{
    const float SC = sqrtf(5.0f * 1.44269504088896340736f);  // sqrt(5*log2e)
    int gid = blockIdx.x * 256 + threadIdx.x;
    if (gid < 4 * N) acc[gid] = 0.f;
    if (gid == 0) out[0] = 0.f;

    int row  = blockIdx.x * 4 + (threadIdx.x >> 6);
    int lane = threadIdx.x & 63;
    float2 u = h1[(size_t)row * 64 + lane];
    float2 w = h2[(size_t)row * 64 + lane];
    float ss1 = u.x * u.x + u.y * u.y;
    float ss2 = w.x * w.x + w.y * w.y;
    float s12 = u.x * w.x + u.y * w.y;
#pragma unroll
    for (int off = 32; off > 0; off >>= 1) {
        ss1 += __shfl_xor(ss1, off, 64);
        ss2 += __shfl_xor(ss2, off, 64);
        s12 += __shfl_xor(s12, off, 64);
    }
    float n1 = fmaxf(sqrtf(ss1), 1e-12f);
    float n2 = fmaxf(sqrtf(ss2), 1e-12f);
    float c1 = SC / n1, c2 = SC / n2;
    int p1 = __builtin_amdgcn_cvt_pk_fp8_f32(u.x * c1, u.y * c1, 0, false);
    int p2 = __builtin_amdgcn_cvt_pk_fp8_f32(w.x * c2, w.y * c2, 0, false);
    g1b[(size_t)row * 64 + lane] = (unsigned short)(p1 & 0xffff);
    g2b[(size_t)row * 64 + lane] = (unsigned short)(p2 & 0xffff);
    if (lane == 0) d12[row] = 5.f * s12 / (n1 * n2);
}

// z=0: g1.g1 -> r11 ; z=1: g1.g2 -> r12 rows + c12 cols ; z=2: g2.g2 -> r22.
// Block 512 thr (8 waves: wi=wave>>2 row-half, wj=wave&3 col-quarter).
// nT=4 128x128 tiles. A in regs (K=128 fp8). Per ks: 1 ds_read_b64 feeds
// 2 MFMAs. SYM tiles: (i,(i+d)%64), d=4y..4y+3 for y<8, d=32 for i<32 (y=8).
__global__ __launch_bounds__(512, 4) void gram_mfma_kernel(
    const unsigned char* __restrict__ g1b, const unsigned char* __restrict__ g2b,
    float* __restrict__ r11, float* __restrict__ r12,
    float* __restrict__ c12, float* __restrict__ r22, int N)
{
    const int z = blockIdx.z;
    const bool SYM = (z != 1);
    const unsigned char* X; const unsigned char* Y; float* rrow;
    if (z == 0)      { X = g1b; Y = g1b; rrow = r11; }
    else if (z == 1) { X = g1b; Y = g2b; rrow = r12; }
    else             { X = g2b; Y = g2b; rrow = r22; }
    float* ctgt = SYM ? rrow : c12;

    const int iTile = blockIdx.x;
    int nT = 4, dBase = 0;
    if (SYM) {
        if (blockIdx.y < 8)                     { dBase = blockIdx.y * 4; }
        else if (blockIdx.y == 8 && iTile < 32) { nT = 1; dBase = 32; }
        else return;
    }

    __shared__ long Ys[2][2048];   // 2 x 16 KB double buffer (swizzled)

    const int tx   = threadIdx.x;
    const int lane = tx & 63;
    const int l32  = lane & 31, lhi = lane >> 5;
    const int wave = tx >> 6;
    const int wi   = wave >> 2, wj = wave & 3;
    const int iBase = iTile * 128;

    auto jTileOf = [&](int t) {
        return SYM ? ((iTile + dBase + t) & 63) : ((int)blockIdx.y * 4 + t);
    };

    // A-fragments: a[st][ks], rows iBase + wi*64 + st*32 + l32, k = ks*16+lhi*8
    long a[2][8];
#pragma unroll
    for (int st = 0; st < 2; ++st) {
        const unsigned char* xp =
            X + (size_t)(iBase + wi * 64 + st * 32 + l32) * D + lhi * 8;
#pragma unroll
        for (int ks = 0; ks < 8; ++ks)
            a[st][ks] = *(const long*)(xp + ks * 16);
    }

    float racc0[16], racc1[16];
#pragma unroll
    for (int r = 0; r < 16; ++r) { racc0[r] = 0.f; racc1[r] = 0.f; }
    float cp[4] = {0.f, 0.f, 0.f, 0.f};

    // prefetch first tile: 512 thr x 2 long2 = 16 KB
    long2 v[2];
    {
        const long2* yp = (const long2*)(Y + (size_t)jTileOf(0) * 128 * D);
        v[0] = yp[tx]; v[1] = yp[512 + tx];
    }

    const int j0 = wj * 32 + l32;   // this wave's B column
    const int sw = l32 & 15;        // swizzle key (j0 & 15)

    for (int t = 0; t < nT; ++t) {
        long* buf = Ys[t & 1];
        // write staged tile (swizzled): buf was last read at t-2; the t-1
        // barrier orders those reads before these writes.
#pragma unroll
        for (int i = 0; i < 2; ++i) {
            int chunk = i * 512 + tx;
            int j = chunk >> 3, c = chunk & 7;
            int base = ((2 * c) ^ (j & 15)) & ~1;
            long2 w = v[i];
            if (j & 1) { long tmp = w.x; w.x = w.y; w.y = tmp; }
            *(long2*)&buf[j * 16 + base] = w;
        }
        __syncthreads();   // writes visible; no vmem outstanding here
        // prefetch next tile AFTER the barrier: latency covered by MFMA+epi
        if (t + 1 < nT) {
            const long2* yp =
                (const long2*)(Y + (size_t)jTileOf(t + 1) * 128 * D);
            v[0] = yp[tx]; v[1] = yp[512 + tx];
        }

        f32x16 acc0, acc1;
#pragma unroll
        for (int r = 0; r < 16; ++r) { acc0[r] = 0.f; acc1[r] = 0.f; }

#pragma unroll
        for (int ks = 0; ks < 8; ++ks) {
            long b = buf[j0 * 16 + ((2 * ks + lhi) ^ sw)];
            acc0 = __builtin_amdgcn_mfma_f32_32x32x16_fp8_fp8(a[0][ks], b, acc0, 0, 0, 0);
            acc1 = __builtin_amdgcn_mfma_f32_32x32x16_fp8_fp8(a[1][ks], b, acc1, 0, 0, 0);
        }

        // epilogue: exp2 + row sums in regs; col partial in 1 reg per tile
        float c = 0.f;
#pragma unroll
        for (int r = 0; r < 16; ++r) {
            float e0 = __builtin_amdgcn_exp2f(acc0[r]);
            float e1 = __builtin_amdgcn_exp2f(acc1[r]);
            racc0[r] += e0;
            racc1[r] += e1;
            c += e0 + e1;
        }
        if (!SYM || (dBase + t) != 0) cp[t] = c;   // skip diag tile cols
    }

    // flush row sums: butterfly over 32 col-lanes; C row=(r&3)+8*(r>>2)+4*lhi
#pragma unroll
    for (int r = 0; r < 16; ++r) {
        float s0 = racc0[r], s1 = racc1[r];
#pragma unroll
        for (int off = 1; off < 32; off <<= 1) {
            s0 += __shfl_xor(s0, off, 64);
            s1 += __shfl_xor(s1, off, 64);
        }
        if (l32 == 0) {
            int rowm = (r & 3) + 8 * (r >> 2) + 4 * lhi;
            atomicAdd(&rrow[iBase + wi * 64 + rowm], s0);
            atomicAdd(&rrow[iBase + wi * 64 + 32 + rowm], s1);
        }
    }

    // flush col sums (fire-and-forget; nothing waits on these)
#pragma unroll
    for (int t = 0; t < 4; ++t) {
        if (t >= nT) break;
        if (SYM && (dBase + t) == 0) continue;
        float c = cp[t];
        c += __shfl_xor(c, 32, 64);   // merge lhi halves
        if (lane < 32)
            atomicAdd(&ctgt[jTileOf(t) * 128 + j0], c);
    }
}

// loss_i = 0.5*(log(r11+r12-e5) + log(r22+c12-e5)) - d12 ; out = mean
__global__ __launch_bounds__(256) void loss_reduce_kernel(
    const float* __restrict__ r11, const float* __restrict__ r12,
    const float* __restrict__ c12, const float* __restrict__ r22,
    const float* __restrict__ d12, float* __restrict__ out, int N)
{
    __shared__ float sm[256];
    float s = 0.f;
    for (int i = blockIdx.x * 256 + threadIdx.x; i < N; i += gridDim.x * 256) {
        float neg1 = r11[i] + r12[i] - E5;
        float neg2 = r22[i] + c12[i] - E5;
        s += 0.5f * (logf(neg1) + logf(neg2)) - d12[i];
    }
    sm[threadIdx.x] = s;
    __syncthreads();
    for (int w = 128; w > 0; w >>= 1) {
        if (threadIdx.x < w) sm[threadIdx.x] += sm[threadIdx.x + w];
        __syncthreads();
    }
    if (threadIdx.x == 0) atomicAdd(out, sm[0] / (float)N);
}

extern "C" void kernel_launch(void* const* d_in, const int* in_sizes, int n_in,
                              void* d_out, int out_size, void* d_ws, size_t ws_size,
                              hipStream_t stream) {
    const float* h1 = (const float*)d_in[0];
    const float* h2 = (const float*)d_in[1];
    const int N = in_sizes[0] / D;   // 8192

    unsigned char* g1b = (unsigned char*)d_ws;
    unsigned char* g2b = g1b + (size_t)N * D;
    float* acc  = (float*)(g2b + (size_t)N * D);
    float* r11  = acc;
    float* r12  = acc + N;
    float* c12  = acc + 2 * N;
    float* r22  = acc + 3 * N;
    float* d12  = acc + 4 * N;
    float* out  = (float*)d_out;

    normalize_kernel<<<N / 4, 256, 0, stream>>>(
        (const float2*)h1, (const float2*)h2,
        (unsigned short*)g1b, (unsigned short*)g2b, d12, acc, out, N);

    // SYM: y<8 -> d=4y..4y+3; y==8,i<32 -> d=32. cross: y<16 -> j=4y..4y+3
    dim3 grid(N / 128, 16, 3);
    gram_mfma_kernel<<<grid, 512, 0, stream>>>(g1b, g2b, r11, r12, c12, r22, N);

    loss_reduce_kernel<<<32, 256, 0, stream>>>(r11, r12, c12, r22, d12, out, N);
}

// Round 9
// 117.456 us; speedup vs baseline: 1.3764x; 1.3764x over previous
//
#include <hip/hip_runtime.h>
#include <math.h>

// InfoNCE (NT-Xent), N=8192, D=128, fp32 in, scalar fp32 out.
// Unified stacked Gram: G = [g1n; g2n] * sqrt(5*log2e) in fp8 e4m3 (2N x 128).
// rsum[k] = sum_j exp(G_k . G_j) over all 2N columns, computed on the lower
// triangle only (symmetry: col sums of a tile are row sums of its transpose).
// neg1_i = rsum[i]-E5, neg2_i = rsum[N+i]-E5; pos term d12 exact in fp32.
// K-loop: double-buffered LDS, one barrier/tile, prefetch AFTER the barrier
// (no global op in front of any barrier), col atomics deferred to block end.

constexpr int D = 128;
constexpr float E5 = 148.4131591025766f;   // e^5 (diag self-term)

typedef __attribute__((ext_vector_type(16))) float f32x16;  // 32x32 MFMA acc

__global__ __launch_bounds__(256) void normalize_kernel(
    const float2* __restrict__ h1, const float2* __restrict__ h2,
    unsigned short* __restrict__ Gx, float* __restrict__ d12,
    float* __restrict__ rsum, float* __restrict__ out, int N)
{
    const float SC = sqrtf(5.0f * 1.44269504088896340736f);  // sqrt(5*log2e)
    int gid = blockIdx.x * 256 + threadIdx.x;
    if (gid < 2 * N) rsum[gid] = 0.f;
    if (gid == 0) out[0] = 0.f;

    int row  = blockIdx.x * 4 + (threadIdx.x >> 6);
    int lane = threadIdx.x & 63;
    float2 u = h1[(size_t)row * 64 + lane];
    float2 w = h2[(size_t)row * 64 + lane];
    float ss1 = u.x * u.x + u.y * u.y;
    float ss2 = w.x * w.x + w.y * w.y;
    float s12 = u.x * w.x + u.y * w.y;
#pragma unroll
    for (int off = 32; off > 0; off >>= 1) {
        ss1 += __shfl_xor(ss1, off, 64);
        ss2 += __shfl_xor(ss2, off, 64);
        s12 += __shfl_xor(s12, off, 64);
    }
    float n1 = fmaxf(sqrtf(ss1), 1e-12f);
    float n2 = fmaxf(sqrtf(ss2), 1e-12f);
    float c1 = SC / n1, c2 = SC / n2;
    int p1 = __builtin_amdgcn_cvt_pk_fp8_f32(u.x * c1, u.y * c1, 0, false);
    int p2 = __builtin_amdgcn_cvt_pk_fp8_f32(w.x * c2, w.y * c2, 0, false);
    Gx[(size_t)row * 64 + lane]           = (unsigned short)(p1 & 0xffff);
    Gx[(size_t)(N + row) * 64 + lane]     = (unsigned short)(p2 & 0xffff);
    if (lane == 0) d12[row] = 5.f * s12 / (n1 * n2);
}

// Strips of 128 rows over 2N=16384 -> 128 strips. Tiles (I, (I+d)&127):
// y<16 -> d=4y..4y+3 (nT=4); y==16, I<64 -> d=64 (nT=1). Each unordered
// strip pair exactly once. Block 256 thr (4 waves), wave tile 64x64.
// d==0 tile: row sums only (tile is symmetric); else rows of I + cols -> J.
__global__ __launch_bounds__(256, 2) void gram_mfma_kernel(
    const unsigned char* __restrict__ G, float* __restrict__ rsum, int N)
{
    const int I = blockIdx.x;
    int nT = 4, dBase = 0;
    if (blockIdx.y < 16) { dBase = blockIdx.y * 4; }
    else if (I < 64)     { nT = 1; dBase = 64; }
    else return;

    __shared__ long Ys[2][2048];   // 2 x 16 KB double buffer (swizzled)

    const int tx   = threadIdx.x;
    const int lane = tx & 63;
    const int l32  = lane & 31, lhi = lane >> 5;
    const int wi   = (tx >> 6) >> 1, wj = (tx >> 6) & 1;
    const int iBase = I * 128;

    auto jStrip = [&](int t) { return (I + dBase + t) & 127; };

    // A-fragments: a[st][ks], rows iBase + wi*64 + st*32 + l32, k = ks*16+lhi*8
    long a[2][8];
#pragma unroll
    for (int st = 0; st < 2; ++st) {
        const unsigned char* xp =
            G + (size_t)(iBase + wi * 64 + st * 32 + l32) * D + lhi * 8;
#pragma unroll
        for (int ks = 0; ks < 8; ++ks)
            a[st][ks] = *(const long*)(xp + ks * 16);
    }

    float racc0[16], racc1[16];
#pragma unroll
    for (int r = 0; r < 16; ++r) { racc0[r] = 0.f; racc1[r] = 0.f; }
    float cpA[4] = {0.f, 0.f, 0.f, 0.f};   // col partials, j0 half
    float cpB[4] = {0.f, 0.f, 0.f, 0.f};   // col partials, j1 half

    // prefetch first tile: 256 thr x 4 long2 = 16 KB
    long2 v[4];
    {
        const long2* yp = (const long2*)(G + (size_t)jStrip(0) * 128 * D);
#pragma unroll
        for (int i = 0; i < 4; ++i) v[i] = yp[i * 256 + tx];
    }

    const int j0 = wj * 64 + l32;
    const int j1 = j0 + 32;
    const int sw = l32 & 15;   // swizzle key (== j0&15 == j1&15)

    for (int t = 0; t < nT; ++t) {
        long* buf = Ys[t & 1];
        // stage (swizzled). Safe: buf last read at t-2, barrier t-1 between.
#pragma unroll
        for (int i = 0; i < 4; ++i) {
            int chunk = i * 256 + tx;
            int j = chunk >> 3, c = chunk & 7;
            int base = ((2 * c) ^ (j & 15)) & ~1;
            long2 w = v[i];
            if (j & 1) { long tmp = w.x; w.x = w.y; w.y = tmp; }
            *(long2*)&buf[j * 16 + base] = w;
        }
        __syncthreads();   // only LDS writes outstanding here (cheap drain)

        // prefetch next tile AFTER the barrier; its vmcnt wait lands at the
        // next iteration's staging writes, covered by MFMA + epilogue below
        if (t + 1 < nT) {
            const long2* yp =
                (const long2*)(G + (size_t)jStrip(t + 1) * 128 * D);
#pragma unroll
            for (int i = 0; i < 4; ++i) v[i] = yp[i * 256 + tx];
        }

        f32x16 acc00, acc01, acc10, acc11;
#pragma unroll
        for (int r = 0; r < 16; ++r) {
            acc00[r] = 0.f; acc01[r] = 0.f; acc10[r] = 0.f; acc11[r] = 0.f;
        }

#pragma unroll
        for (int ks = 0; ks < 8; ++ks) {
            int f = 2 * ks + lhi;
            long b0 = buf[j0 * 16 + (f ^ sw)];
            long b1 = buf[j1 * 16 + (f ^ sw)];
            acc00 = __builtin_amdgcn_mfma_f32_32x32x16_fp8_fp8(a[0][ks], b0, acc00, 0, 0, 0);
            acc10 = __builtin_amdgcn_mfma_f32_32x32x16_fp8_fp8(a[1][ks], b0, acc10, 0, 0, 0);
            acc01 = __builtin_amdgcn_mfma_f32_32x32x16_fp8_fp8(a[0][ks], b1, acc01, 0, 0, 0);
            acc11 = __builtin_amdgcn_mfma_f32_32x32x16_fp8_fp8(a[1][ks], b1, acc11, 0, 0, 0);
        }

        // epilogue: exp2 + row sums in regs; col partials in regs (deferred)
        float c0 = 0.f, c1 = 0.f;
#pragma unroll
        for (int r = 0; r < 16; ++r) {
            float e00 = __builtin_amdgcn_exp2f(acc00[r]);
            float e01 = __builtin_amdgcn_exp2f(acc01[r]);
            float e10 = __builtin_amdgcn_exp2f(acc10[r]);
            float e11 = __builtin_amdgcn_exp2f(acc11[r]);
            racc0[r] += e00 + e01;
            racc1[r] += e10 + e11;
            c0 += e00 + e10;
            c1 += e01 + e11;
        }
        if ((dBase + t) != 0) { cpA[t] = c0; cpB[t] = c1; }   // skip diag tile
    }

    // flush row sums: butterfly over 32 col-lanes; C row=(r&3)+8*(r>>2)+4*lhi
#pragma unroll
    for (int r = 0; r < 16; ++r) {
        float s0 = racc0[r], s1 = racc1[r];
#pragma unroll
        for (int off = 1; off < 32; off <<= 1) {
            s0 += __shfl_xor(s0, off, 64);
            s1 += __shfl_xor(s1, off, 64);
        }
        if (l32 == 0) {
            int rowm = (r & 3) + 8 * (r >> 2) + 4 * lhi;
            atomicAdd(&rsum[iBase + wi * 64 + rowm], s0);
            atomicAdd(&rsum[iBase + wi * 64 + 32 + rowm], s1);
        }
    }

    // flush col sums (fire-and-forget; nothing waits on these)
#pragma unroll
    for (int t = 0; t < 4; ++t) {
        if (t >= nT) break;
        if ((dBase + t) == 0) continue;
        float c0 = cpA[t], c1 = cpB[t];
        c0 += __shfl_xor(c0, 32, 64);   // merge lhi halves
        c1 += __shfl_xor(c1, 32, 64);
        if (lane < 32) {
            int jb = jStrip(t) * 128;
            atomicAdd(&rsum[jb + j0], c0);
            atomicAdd(&rsum[jb + j1], c1);
        }
    }
}

// loss_i = 0.5*(log(rsum[i]-e5) + log(rsum[N+i]-e5)) - d12 ; out = mean
__global__ __launch_bounds__(256) void loss_reduce_kernel(
    const float* __restrict__ rsum, const float* __restrict__ d12,
    float* __restrict__ out, int N)
{
    __shared__ float sm[256];
    float s = 0.f;
    for (int i = blockIdx.x * 256 + threadIdx.x; i < N; i += gridDim.x * 256) {
        float neg1 = rsum[i] - E5;
        float neg2 = rsum[N + i] - E5;
        s += 0.5f * (logf(neg1) + logf(neg2)) - d12[i];
    }
    sm[threadIdx.x] = s;
    __syncthreads();
    for (int w = 128; w > 0; w >>= 1) {
        if (threadIdx.x < w) sm[threadIdx.x] += sm[threadIdx.x + w];
        __syncthreads();
    }
    if (threadIdx.x == 0) atomicAdd(out, sm[0] / (float)N);
}

extern "C" void kernel_launch(void* const* d_in, const int* in_sizes, int n_in,
                              void* d_out, int out_size, void* d_ws, size_t ws_size,
                              hipStream_t stream) {
    const float* h1 = (const float*)d_in[0];
    const float* h2 = (const float*)d_in[1];
    const int N = in_sizes[0] / D;   // 8192

    unsigned char* G = (unsigned char*)d_ws;               // 2N x 128 fp8
    float* rsum = (float*)(G + (size_t)2 * N * D);          // 2N
    float* d12  = rsum + 2 * N;                              // N
    float* out  = (float*)d_out;

    normalize_kernel<<<N / 4, 256, 0, stream>>>(
        (const float2*)h1, (const float2*)h2,
        (unsigned short*)G, d12, rsum, out, N);

    dim3 grid(128, 17, 1);
    gram_mfma_kernel<<<grid, 256, 0, stream>>>(G, rsum, N);

    loss_reduce_kernel<<<32, 256, 0, stream>>>(rsum, d12, out, N);
}

// Round 10
// 107.876 us; speedup vs baseline: 1.4986x; 1.0888x over previous
//
#include <hip/hip_runtime.h>
#include <math.h>

// InfoNCE (NT-Xent), N=8192, D=128, fp32 in, scalar fp32 out.
// Unified stacked Gram G=[g1n;g2n]*sqrt(5*log2e), fp8 e4m3, 2N x 128, stored
// FRAGMENT-MAJOR: P[(row>>5)*16 + f][row&31] holds bytes k=8f..8f+7 of row.
// A- and B-MFMA fragments are then single fully-coalesced 512B/wave loads
// straight from L2 (G = 2MB, L2-resident per XCD) -> NO LDS, NO barriers.
// rsum[k] = sum_j exp(G_k.G_j) via lower-triangle tiles (col sums of a tile
// are row sums of its transpose). neg_i = rsum[i]-E5; pos term d12 in fp32.

constexpr int D = 128;
constexpr float E5 = 148.4131591025766f;   // e^5 (diag self-term)

typedef __attribute__((ext_vector_type(16))) float f32x16;  // 32x32 MFMA acc

__global__ __launch_bounds__(256) void normalize_kernel(
    const float2* __restrict__ h1, const float2* __restrict__ h2,
    unsigned short* __restrict__ P16, float* __restrict__ d12,
    float* __restrict__ rsum, float* __restrict__ out, int N)
{
    const float SC = sqrtf(5.0f * 1.44269504088896340736f);  // sqrt(5*log2e)
    int gid = blockIdx.x * 256 + threadIdx.x;
    if (gid < 2 * N) rsum[gid] = 0.f;
    if (gid == 0) out[0] = 0.f;

    int row  = blockIdx.x * 4 + (threadIdx.x >> 6);
    int lane = threadIdx.x & 63;
    float2 u = h1[(size_t)row * 64 + lane];
    float2 w = h2[(size_t)row * 64 + lane];
    float ss1 = u.x * u.x + u.y * u.y;
    float ss2 = w.x * w.x + w.y * w.y;
    float s12 = u.x * w.x + u.y * w.y;
#pragma unroll
    for (int off = 32; off > 0; off >>= 1) {
        ss1 += __shfl_xor(ss1, off, 64);
        ss2 += __shfl_xor(ss2, off, 64);
        s12 += __shfl_xor(s12, off, 64);
    }
    float n1 = fmaxf(sqrtf(ss1), 1e-12f);
    float n2 = fmaxf(sqrtf(ss2), 1e-12f);
    float c1 = SC / n1, c2 = SC / n2;
    int p1 = __builtin_amdgcn_cvt_pk_fp8_f32(u.x * c1, u.y * c1, 0, false);
    int p2 = __builtin_amdgcn_cvt_pk_fp8_f32(w.x * c2, w.y * c2, 0, false);
    // lane covers bytes k=2*lane,2*lane+1 -> frag f=lane>>2, slot lane&3
    int r1 = row, r2 = N + row;
    int fi = lane >> 2, li = lane & 3;
    P16[(size_t)(((r1 >> 5) * 16 + fi) * 128) + (r1 & 31) * 4 + li] =
        (unsigned short)(p1 & 0xffff);
    P16[(size_t)(((r2 >> 5) * 16 + fi) * 128) + (r2 & 31) * 4 + li] =
        (unsigned short)(p2 & 0xffff);
    if (lane == 0) d12[row] = 5.f * s12 / (n1 * n2);
}

// Strips of 128 rows over 2N=16384 -> 128 strips. Tiles (I,(I+d)&127):
// y<16 -> d=4y..4y+3 (nT=4); y==16, I<64 -> d=64 (nT=1). Each unordered
// strip pair exactly once. Block 256 thr (4 waves), wave tile 64x64.
// No LDS, no barriers: A and B frags load directly from packed P (L2-hot).
// Fragment address for (row, f): ((row>>5)*16 + f)*256 + (row&31)*8 bytes.
__global__ __launch_bounds__(256, 2) void gram_mfma_kernel(
    const unsigned char* __restrict__ P, float* __restrict__ rsum, int N)
{
    const int I = blockIdx.x;
    int nT = 4, dBase = 0;
    if (blockIdx.y < 16) { dBase = blockIdx.y * 4; }
    else if (I < 64)     { nT = 1; dBase = 64; }
    else return;

    const int tx   = threadIdx.x;
    const int lane = tx & 63;
    const int l32  = lane & 31, lhi = lane >> 5;
    const int wi   = (tx >> 6) >> 1, wj = (tx >> 6) & 1;
    const int iBase = I * 128;

    // A-fragments: a[st][ks] = frag(row = iBase+wi*64+st*32+l32, f = 2ks+lhi)
    long a[2][8];
#pragma unroll
    for (int st = 0; st < 2; ++st) {
        const unsigned char* xp =
            P + (size_t)((I * 4 + wi * 2 + st) * 16 + lhi) * 256 + l32 * 8;
#pragma unroll
        for (int ks = 0; ks < 8; ++ks)
            a[st][ks] = *(const long*)(xp + ks * 512);
    }

    float racc0[16], racc1[16];
#pragma unroll
    for (int r = 0; r < 16; ++r) { racc0[r] = 0.f; racc1[r] = 0.f; }
    float cpA[4] = {0.f, 0.f, 0.f, 0.f};
    float cpB[4] = {0.f, 0.f, 0.f, 0.f};

    const int j0 = wj * 64 + l32;
    const int j1 = j0 + 32;

    for (int t = 0; t < nT; ++t) {
        const int J = (I + dBase + t) & 127;
        const unsigned char* pb =
            P + (size_t)((J * 4 + wj * 2) * 16 + lhi) * 256 + l32 * 8;

        // B-fragments: same per-lane pattern as A; 512B/wave per load
        long b0[8], b1[8];
#pragma unroll
        for (int ks = 0; ks < 8; ++ks) {
            b0[ks] = *(const long*)(pb + ks * 512);
            b1[ks] = *(const long*)(pb + 4096 + ks * 512);
        }

        f32x16 acc00, acc01, acc10, acc11;
#pragma unroll
        for (int r = 0; r < 16; ++r) {
            acc00[r] = 0.f; acc01[r] = 0.f; acc10[r] = 0.f; acc11[r] = 0.f;
        }

#pragma unroll
        for (int ks = 0; ks < 8; ++ks) {
            acc00 = __builtin_amdgcn_mfma_f32_32x32x16_fp8_fp8(a[0][ks], b0[ks], acc00, 0, 0, 0);
            acc10 = __builtin_amdgcn_mfma_f32_32x32x16_fp8_fp8(a[1][ks], b0[ks], acc10, 0, 0, 0);
            acc01 = __builtin_amdgcn_mfma_f32_32x32x16_fp8_fp8(a[0][ks], b1[ks], acc01, 0, 0, 0);
            acc11 = __builtin_amdgcn_mfma_f32_32x32x16_fp8_fp8(a[1][ks], b1[ks], acc11, 0, 0, 0);
        }

        // epilogue: exp2 + row sums in regs; col partials in regs (deferred)
        float c0 = 0.f, c1 = 0.f;
#pragma unroll
        for (int r = 0; r < 16; ++r) {
            float e00 = __builtin_amdgcn_exp2f(acc00[r]);
            float e01 = __builtin_amdgcn_exp2f(acc01[r]);
            float e10 = __builtin_amdgcn_exp2f(acc10[r]);
            float e11 = __builtin_amdgcn_exp2f(acc11[r]);
            racc0[r] += e00 + e01;
            racc1[r] += e10 + e11;
            c0 += e00 + e10;
            c1 += e01 + e11;
        }
        if ((dBase + t) != 0) { cpA[t] = c0; cpB[t] = c1; }   // skip diag tile
    }

    // flush row sums: butterfly over 32 col-lanes; C row=(r&3)+8*(r>>2)+4*lhi
#pragma unroll
    for (int r = 0; r < 16; ++r) {
        float s0 = racc0[r], s1 = racc1[r];
#pragma unroll
        for (int off = 1; off < 32; off <<= 1) {
            s0 += __shfl_xor(s0, off, 64);
            s1 += __shfl_xor(s1, off, 64);
        }
        if (l32 == 0) {
            int rowm = (r & 3) + 8 * (r >> 2) + 4 * lhi;
            atomicAdd(&rsum[iBase + wi * 64 + rowm], s0);
            atomicAdd(&rsum[iBase + wi * 64 + 32 + rowm], s1);
        }
    }

    // flush col sums (fire-and-forget; nothing waits on these)
#pragma unroll
    for (int t = 0; t < 4; ++t) {
        if (t >= nT) break;
        if ((dBase + t) == 0) continue;
        float c0 = cpA[t], c1 = cpB[t];
        c0 += __shfl_xor(c0, 32, 64);   // merge lhi halves
        c1 += __shfl_xor(c1, 32, 64);
        if (lane < 32) {
            int jb = ((I + dBase + t) & 127) * 128;
            atomicAdd(&rsum[jb + j0], c0);
            atomicAdd(&rsum[jb + j1], c1);
        }
    }
}

// loss_i = 0.5*(log(rsum[i]-e5) + log(rsum[N+i]-e5)) - d12 ; out = mean
__global__ __launch_bounds__(256) void loss_reduce_kernel(
    const float* __restrict__ rsum, const float* __restrict__ d12,
    float* __restrict__ out, int N)
{
    __shared__ float sm[256];
    float s = 0.f;
    for (int i = blockIdx.x * 256 + threadIdx.x; i < N; i += gridDim.x * 256) {
        float neg1 = rsum[i] - E5;
        float neg2 = rsum[N + i] - E5;
        s += 0.5f * (logf(neg1) + logf(neg2)) - d12[i];
    }
    sm[threadIdx.x] = s;
    __syncthreads();
    for (int w = 128; w > 0; w >>= 1) {
        if (threadIdx.x < w) sm[threadIdx.x] += sm[threadIdx.x + w];
        __syncthreads();
    }
    if (threadIdx.x == 0) atomicAdd(out, sm[0] / (float)N);
}

extern "C" void kernel_launch(void* const* d_in, const int* in_sizes, int n_in,
                              void* d_out, int out_size, void* d_ws, size_t ws_size,
                              hipStream_t stream) {
    const float* h1 = (const float*)d_in[0];
    const float* h2 = (const float*)d_in[1];
    const int N = in_sizes[0] / D;   // 8192

    unsigned char* P = (unsigned char*)d_ws;                // 2N x 128 fp8, frag-major
    float* rsum = (float*)(P + (size_t)2 * N * D);          // 2N
    float* d12  = rsum + 2 * N;                             // N
    float* out  = (float*)d_out;

    normalize_kernel<<<N / 4, 256, 0, stream>>>(
        (const float2*)h1, (const float2*)h2,
        (unsigned short*)P, d12, rsum, out, N);

    dim3 grid(128, 17, 1);
    gram_mfma_kernel<<<grid, 256, 0, stream>>>(P, rsum, N);

    loss_reduce_kernel<<<32, 256, 0, stream>>>(rsum, d12, out, N);
}